// Round 3
// baseline (287.770 us; speedup 1.0000x reference)
//
#include <hip/hip_runtime.h>

// Problem constants (fixed by reference): B=32, N=512, M=64 grid coords,
// 2*SIGMA^2 = 128, BG_RATIO = 0.15, output [32][513][4096] fp32.
#define NPTS 512
#define KINV (-0.0078125f)   // -1/(2*sigma^2) = -1/128, exact in fp32

typedef float v4f __attribute__((ext_vector_type(4)));  // native vec for nt-store

// Kernel 1: one block per (batch, i). Computes per-column softmax denominator
// S[i][j] = sum_n exp(-(ydis[n,i]+xdis[n,j])/128) + bg, tracks min_dis directly,
// writes 1/S to workspace and the background output row (row 512).
// LDS layout packs (x[n], (y[n]-ci)^2) as float2 so the inner loop reads two
// points per wave-uniform ds_read_b128 (halves LDS-pipe pressure vs b32 pairs).
__global__ __launch_bounds__(256) void k_denom(
    const float* __restrict__ pts,    // [32][512][2]
    const float* __restrict__ st,     // [32]
    const float* __restrict__ cood,   // [64]
    float* __restrict__ out,          // [32][513][4096]
    float* __restrict__ rinv)         // ws: [32][64][64]
{
    __shared__ __align__(16) float2 s_p[NPTS];   // (x, yd^2) pairs, 4 KB
    __shared__ float s_sum[4][64];
    __shared__ float s_min[4][64];

    const int b   = blockIdx.x >> 6;
    const int i   = blockIdx.x & 63;
    const int tid = threadIdx.x;
    const float ci = cood[i];

    for (int t = tid; t < NPTS; t += 256) {
        float2 p = ((const float2*)pts)[b * NPTS + t];
        float yd = p.y - ci;
        s_p[t] = make_float2(p.x, yd * yd);
    }
    __syncthreads();

    // Thread owns column j = tid&63 (one wave = one full j-row), quarter
    // q = tid>>6 of the n-range. All LDS reads are wave-uniform broadcasts.
    const int j = tid & 63;
    const int q = tid >> 6;
    const float cj = cood[j];
    float sum0 = 0.0f, sum1 = 0.0f;
    float mn = 3.4e38f;
    const v4f* sp4 = (const v4f*)s_p;            // 256 entries = 2 points each
    const int t0 = q * 64;
    #pragma unroll 8
    for (int t = t0; t < t0 + 64; ++t) {
        v4f v = sp4[t];                          // x0, yd0, x1, yd1
        float xd0 = v.x - cj;
        float a0  = fmaf(xd0, xd0, v.y);
        float xd1 = v.z - cj;
        float a1  = fmaf(xd1, xd1, v.w);
        sum0 += __expf(a0 * KINV);
        sum1 += __expf(a1 * KINV);
        mn = fminf(mn, fminf(a0, a1));
    }
    s_sum[q][j] = sum0 + sum1;
    s_min[q][j] = mn;
    __syncthreads();

    if (tid < 64) {
        float S = (s_sum[0][tid] + s_sum[1][tid]) + (s_sum[2][tid] + s_sum[3][tid]);
        float m = fminf(fminf(s_min[0][tid], s_min[1][tid]),
                        fminf(s_min[2][tid], s_min[3][tid]));
        m = fmaxf(m, 0.0f);                    // reference's clip(min_dis, 0)
        float dd = st[b] * 0.15f;              // BG_RATIO
        float bd = dd - sqrtf(m);
        float bg = __expf(bd * bd * KINV);
        S += bg;
        float r = 1.0f / S;
        rinv[b * 4096 + i * 64 + tid] = r;
        out[(size_t)(b * 513 + 512) * 4096 + i * 64 + tid] = bg * r;
    }
}

// Kernel 2: one block per (batch, 16-row chunk). out[n][i*64+j] =
// ey[n,i] * ex[n,j] * rinv[i,j], streamed as fully-coalesced nontemporal
// float4 stores (output is never re-read; track the ~6.5 TB/s fill ceiling).
__global__ __launch_bounds__(256) void k_write(
    const float* __restrict__ pts,
    const float* __restrict__ cood,
    const float* __restrict__ rinv,
    float* __restrict__ out)
{
    __shared__ __align__(16) float s_rinv[4096];  // 16 KB
    __shared__ __align__(16) float s_ex[16 * 64]; // 4 KB
    __shared__ float s_ey[16 * 64];               // 4 KB

    const int b   = blockIdx.x >> 5;
    const int n0  = (blockIdx.x & 31) * 16;
    const int tid = threadIdx.x;

    // Stage reciprocal denominators (coalesced float4 from L2-resident ws).
    const float4* rsrc = (const float4*)(rinv + b * 4096);
    for (int t = tid; t < 1024; t += 256)
        ((float4*)s_rinv)[t] = rsrc[t];

    // Compute ex/ey for this 16-row chunk (2048 exps per block).
    for (int t = tid; t < 1024; t += 256) {
        int nl = t >> 6;
        int jj = t & 63;
        float2 p = ((const float2*)pts)[b * NPTS + n0 + nl];
        float c  = cood[jj];
        float xd = p.x - c;
        float yd = p.y - c;
        s_ex[t] = __expf(xd * xd * KINV);
        s_ey[t] = __expf(yd * yd * KINV);
    }
    __syncthreads();

    // 16 rows x 4096 floats = 16384 float4 / 256 threads = 64 iters.
    // Consecutive tid -> consecutive float4: each pass writes one
    // contiguous 16 KB stretch (1 KB per wave-store).
    v4f* dst = (v4f*)(out + (size_t)(b * 513 + n0) * 4096);
    const v4f* sx4 = (const v4f*)s_ex;
    const v4f* sr4 = (const v4f*)s_rinv;
    #pragma unroll 4
    for (int it = 0; it < 64; ++it) {
        int idx = it * 256 + tid;
        int nl  = idx >> 10;       // local row
        int c4  = idx & 1023;      // float4 column
        int ii  = c4 >> 4;         // y-grid index
        int j4  = c4 & 15;         // x-grid float4 index
        v4f ex4 = sx4[nl * 16 + j4];
        v4f r4  = sr4[ii * 16 + j4];
        float ey = s_ey[nl * 64 + ii];
        v4f o = ey * ex4 * r4;
        __builtin_nontemporal_store(o, &dst[idx]);
    }
}

extern "C" void kernel_launch(void* const* d_in, const int* in_sizes, int n_in,
                              void* d_out, int out_size, void* d_ws, size_t ws_size,
                              hipStream_t stream) {
    const float* pts  = (const float*)d_in[0];   // points [32][512][2]
    const float* st   = (const float*)d_in[1];   // st_sizes [32]
    const float* cood = (const float*)d_in[2];   // cood [64]
    float* out  = (float*)d_out;                 // [32][513][4096] fp32
    float* rinv = (float*)d_ws;                  // 512 KB scratch

    k_denom<<<dim3(2048), dim3(256), 0, stream>>>(pts, st, cood, out, rinv);
    k_write<<<dim3(1024), dim3(256), 0, stream>>>(pts, cood, rinv, out);
}

// Round 4
// 286.240 us; speedup vs baseline: 1.0053x; 1.0053x over previous
//
#include <hip/hip_runtime.h>

// Problem constants (fixed by reference): B=32, N=512, M=64 grid coords,
// 2*SIGMA^2 = 128, BG_RATIO = 0.15, output [32][513][4096] fp32.
#define NPTS 512
#define KINV (-0.0078125f)   // -1/(2*sigma^2) = -1/128, exact in fp32

typedef float v4f __attribute__((ext_vector_type(4)));  // native vec for nt-store

// Kernel 1: one block per (batch, i). Computes per-column softmax denominator
// S[i][j] = sum_n exp(-(ydis[n,i]+xdis[n,j])/128) + bg, tracks min_dis directly,
// writes 1/S to workspace and the background output row (row 512).
// LDS packs (x[n], (y[n]-ci)^2) as float2 so the inner loop reads two points
// per wave-uniform ds_read_b128 (broadcast, conflict-free).
__global__ __launch_bounds__(256) void k_denom(
    const float* __restrict__ pts,    // [32][512][2]
    const float* __restrict__ st,     // [32]
    const float* __restrict__ cood,   // [64]
    float* __restrict__ out,          // [32][513][4096]
    float* __restrict__ rinv)         // ws: [32][64][64]
{
    __shared__ __align__(16) float2 s_p[NPTS];   // (x, yd^2) pairs, 4 KB
    __shared__ float s_sum[4][64];
    __shared__ float s_min[4][64];

    const int b   = blockIdx.x >> 6;
    const int i   = blockIdx.x & 63;
    const int tid = threadIdx.x;
    const float ci = cood[i];

    for (int t = tid; t < NPTS; t += 256) {
        float2 p = ((const float2*)pts)[b * NPTS + t];
        float yd = p.y - ci;
        s_p[t] = make_float2(p.x, yd * yd);
    }
    __syncthreads();

    // Thread owns column j = tid&63 (one wave = one full j-row), quarter
    // q = tid>>6 of the n-range. All LDS reads are wave-uniform broadcasts.
    const int j = tid & 63;
    const int q = tid >> 6;
    const float cj = cood[j];
    float sum0 = 0.0f, sum1 = 0.0f;
    float mn0 = 3.4e38f, mn1 = 3.4e38f;          // two chains: break fmin dep
    const v4f* sp4 = (const v4f*)s_p;            // 256 entries = 2 points each
    const int t0 = q * 64;
    #pragma unroll 8
    for (int t = t0; t < t0 + 64; ++t) {
        v4f v = sp4[t];                          // x0, yd0, x1, yd1
        float xd0 = v.x - cj;
        float a0  = fmaf(xd0, xd0, v.y);
        float xd1 = v.z - cj;
        float a1  = fmaf(xd1, xd1, v.w);
        sum0 += __expf(a0 * KINV);
        sum1 += __expf(a1 * KINV);
        mn0 = fminf(mn0, a0);
        mn1 = fminf(mn1, a1);
    }
    s_sum[q][j] = sum0 + sum1;
    s_min[q][j] = fminf(mn0, mn1);
    __syncthreads();

    if (tid < 64) {
        float S = (s_sum[0][tid] + s_sum[1][tid]) + (s_sum[2][tid] + s_sum[3][tid]);
        float m = fminf(fminf(s_min[0][tid], s_min[1][tid]),
                        fminf(s_min[2][tid], s_min[3][tid]));
        m = fmaxf(m, 0.0f);                    // reference's clip(min_dis, 0)
        float dd = st[b] * 0.15f;              // BG_RATIO
        float bd = dd - sqrtf(m);
        float bg = __expf(bd * bd * KINV);
        S += bg;
        float r = 1.0f / S;
        rinv[b * 4096 + i * 64 + tid] = r;
        out[(size_t)(b * 513 + 512) * 4096 + i * 64 + tid] = bg * r;
    }
}

// Kernel 2: one block per (batch, 16-row chunk). out[n][i*64+j] =
// ey[n,i] * ex[n,j] * rinv[i,j], streamed as fully-coalesced nontemporal
// float4 stores. s_rinv is padded to stride 17 float4s: unpadded, the hot
// read sr4[ii*16+j4] hits banks (j4*4..+3) mod 32 for ALL 4 ii-groups in a
// wave -> 4-way serialization on every ds_read_b128; stride 68 floats makes
// the bank start (ii+j4)*4 mod 32 -> conflict-free.
#define RSTRIDE 17   // float4 stride of padded s_rinv rows

__global__ __launch_bounds__(256) void k_write(
    const float* __restrict__ pts,
    const float* __restrict__ cood,
    const float* __restrict__ rinv,
    float* __restrict__ out)
{
    __shared__ __align__(16) float s_rinv[64 * RSTRIDE * 4]; // 17.4 KB, padded
    __shared__ __align__(16) float s_ex[16 * 64];            // 4 KB
    __shared__ float s_ey[16 * 64];                          // 4 KB

    const int b   = blockIdx.x >> 5;
    const int n0  = (blockIdx.x & 31) * 16;
    const int tid = threadIdx.x;

    // Stage reciprocal denominators (coalesced float4 from L2-resident ws),
    // scattering into the padded layout.
    const float4* rsrc = (const float4*)(rinv + b * 4096);
    float4* rdst = (float4*)s_rinv;
    for (int t = tid; t < 1024; t += 256) {
        int row = t >> 4, col = t & 15;
        rdst[row * RSTRIDE + col] = rsrc[t];
    }

    // Compute ex/ey for this 16-row chunk (2048 exps per block).
    for (int t = tid; t < 1024; t += 256) {
        int nl = t >> 6;
        int jj = t & 63;
        float2 p = ((const float2*)pts)[b * NPTS + n0 + nl];
        float c  = cood[jj];
        float xd = p.x - c;
        float yd = p.y - c;
        s_ex[t] = __expf(xd * xd * KINV);
        s_ey[t] = __expf(yd * yd * KINV);
    }
    __syncthreads();

    // 16 rows x 4096 floats = 16384 float4 / 256 threads = 64 iters.
    // Consecutive tid -> consecutive float4: each pass writes one
    // contiguous 16 KB stretch (1 KB per wave-store).
    v4f* dst = (v4f*)(out + (size_t)(b * 513 + n0) * 4096);
    const v4f* sx4 = (const v4f*)s_ex;
    const v4f* sr4 = (const v4f*)s_rinv;
    #pragma unroll 4
    for (int it = 0; it < 64; ++it) {
        int idx = it * 256 + tid;
        int nl  = idx >> 10;       // local row
        int c4  = idx & 1023;      // float4 column
        int ii  = c4 >> 4;         // y-grid index
        int j4  = c4 & 15;         // x-grid float4 index
        v4f ex4 = sx4[nl * 16 + j4];
        v4f r4  = sr4[ii * RSTRIDE + j4];
        float ey = s_ey[nl * 64 + ii];
        v4f o = ey * ex4 * r4;
        __builtin_nontemporal_store(o, &dst[idx]);
    }
}

extern "C" void kernel_launch(void* const* d_in, const int* in_sizes, int n_in,
                              void* d_out, int out_size, void* d_ws, size_t ws_size,
                              hipStream_t stream) {
    const float* pts  = (const float*)d_in[0];   // points [32][512][2]
    const float* st   = (const float*)d_in[1];   // st_sizes [32]
    const float* cood = (const float*)d_in[2];   // cood [64]
    float* out  = (float*)d_out;                 // [32][513][4096] fp32
    float* rinv = (float*)d_ws;                  // 512 KB scratch

    k_denom<<<dim3(2048), dim3(256), 0, stream>>>(pts, st, cood, out, rinv);
    k_write<<<dim3(1024), dim3(256), 0, stream>>>(pts, cood, rinv, out);
}

// Round 5
// 274.960 us; speedup vs baseline: 1.0466x; 1.0410x over previous
//
#include <hip/hip_runtime.h>

// Problem constants (fixed by reference): B=32, N=512, M=64 grid coords,
// 2*SIGMA^2 = 128, BG_RATIO = 0.15, output [32][513][4096] fp32.
#define NPTS 512
#define KINV (-0.0078125f)   // -1/(2*sigma^2) = -1/128, exact in fp32

typedef float v4f __attribute__((ext_vector_type(4)));

// Kernel 1: one block per (batch, i-PAIR). Each ds_read_b128 of 2 raw points
// (x0,y0,x1,y1) feeds BOTH i-rows -> half the LDS-pipe traffic of the 1-i
// version; kernel is then VALU/exp-bound (~8 us). Computes per-column softmax
// denominator S[i][j] = sum_n exp(-dis/128) + bg, tracks min_dis directly,
// writes 1/S to ws and the background output row (row 512).
__global__ __launch_bounds__(256) void k_denom(
    const float* __restrict__ pts,    // [32][512][2]
    const float* __restrict__ st,     // [32]
    const float* __restrict__ cood,   // [64]
    float* __restrict__ out,          // [32][513][4096]
    float* __restrict__ rinv)         // ws: [32][64][64]
{
    __shared__ __align__(16) float s_p[NPTS * 2];   // raw (x,y), 4 KB
    __shared__ float s_sum[4][2][64];
    __shared__ float s_min[4][2][64];

    const int b   = blockIdx.x >> 5;
    const int i0  = (blockIdx.x & 31) * 2;          // i-pair: i0, i0+1
    const int tid = threadIdx.x;
    const float ci0 = cood[i0];
    const float ci1 = cood[i0 + 1];

    // Stage all 512 points: straight coalesced float4 copy (256 x 16 B).
    ((float4*)s_p)[tid] = ((const float4*)(pts + b * (NPTS * 2)))[tid];
    __syncthreads();

    // Thread owns column j = tid&63, quarter q = tid>>6 of the point range
    // (64 float4 = 128 points each). All LDS reads are wave-uniform broadcasts.
    const int j = tid & 63;
    const int q = tid >> 6;
    const float cj = cood[j];
    float sA0 = 0.0f, sA1 = 0.0f, sB0 = 0.0f, sB1 = 0.0f;
    float m00 = 3.4e38f, m01 = 3.4e38f, m10 = 3.4e38f, m11 = 3.4e38f;
    const v4f* sp4 = (const v4f*)s_p;
    const int t0 = q * 64;
    #pragma unroll 8
    for (int t = t0; t < t0 + 64; ++t) {
        v4f v = sp4[t];                    // x0, y0, x1, y1
        float xd0 = v.x - cj; float x20 = xd0 * xd0;
        float xd1 = v.z - cj; float x21 = xd1 * xd1;
        float ya = v.y - ci0; float a00 = fmaf(ya, ya, x20);
        float yb = v.y - ci1; float a01 = fmaf(yb, yb, x20);
        float yc = v.w - ci0; float a10 = fmaf(yc, yc, x21);
        float yd = v.w - ci1; float a11 = fmaf(yd, yd, x21);
        sA0 += __expf(a00 * KINV);  sB0 += __expf(a10 * KINV);
        sA1 += __expf(a01 * KINV);  sB1 += __expf(a11 * KINV);
        m00 = fminf(m00, a00);  m10 = fminf(m10, a10);
        m01 = fminf(m01, a01);  m11 = fminf(m11, a11);
    }
    s_sum[q][0][j] = sA0 + sB0;
    s_sum[q][1][j] = sA1 + sB1;
    s_min[q][0][j] = fminf(m00, m10);
    s_min[q][1][j] = fminf(m01, m11);
    __syncthreads();

    if (tid < 128) {
        int ii = tid >> 6;                 // which i of the pair
        int c  = tid & 63;                 // column j
        float S = (s_sum[0][ii][c] + s_sum[1][ii][c]) +
                  (s_sum[2][ii][c] + s_sum[3][ii][c]);
        float m = fminf(fminf(s_min[0][ii][c], s_min[1][ii][c]),
                        fminf(s_min[2][ii][c], s_min[3][ii][c]));
        m = fmaxf(m, 0.0f);                // reference's clip(min_dis, 0)
        float dd = st[b] * 0.15f;          // BG_RATIO
        float bd = dd - sqrtf(m);
        float bg = __expf(bd * bd * KINV);
        S += bg;
        float r = 1.0f / S;
        int ig = i0 + ii;
        rinv[b * 4096 + ig * 64 + c] = r;
        out[(size_t)(b * 513 + 512) * 4096 + ig * 64 + c] = bg * r;
    }
}

// Kernel 2: one block per (batch, 16-row chunk). out[n][i*64+j] =
// ey[n,i] * ex[n,j] * rinv[i,j]. Per-thread reuse is hoisted: j4 = tid&15 is
// constant, rinv needs only 4 register-resident float4s, ex4 changes once per
// 4 stores -> LDS traffic ~5x lower than the naive loop; kernel is cleanly
// store-BW-bound (269 MB at ~6.4 TB/s ~= 43 us).
#define RSTRIDE 17   // float4 stride of padded s_rinv rows (bank-spread)

__global__ __launch_bounds__(256) void k_write(
    const float* __restrict__ pts,
    const float* __restrict__ cood,
    const float* __restrict__ rinv,
    float* __restrict__ out)
{
    __shared__ __align__(16) float s_rinv[64 * RSTRIDE * 4]; // 17.4 KB padded
    __shared__ __align__(16) float s_ex[16 * 64];            // 4 KB
    __shared__ float s_ey[16 * 64];                          // 4 KB

    const int b   = blockIdx.x >> 5;
    const int n0  = (blockIdx.x & 31) * 16;
    const int tid = threadIdx.x;

    // Stage reciprocal denominators into the padded layout.
    const float4* rsrc = (const float4*)(rinv + b * 4096);
    float4* rdst = (float4*)s_rinv;
    for (int t = tid; t < 1024; t += 256) {
        int row = t >> 4, col = t & 15;
        rdst[row * RSTRIDE + col] = rsrc[t];
    }

    // Compute ex/ey for this 16-row chunk (2048 exps per block).
    for (int t = tid; t < 1024; t += 256) {
        int nl = t >> 6;
        int jj = t & 63;
        float2 p = ((const float2*)pts)[b * NPTS + n0 + nl];
        float c  = cood[jj];
        float xd = p.x - c;
        float yd = p.y - c;
        s_ex[t] = __expf(xd * xd * KINV);
        s_ey[t] = __expf(yd * yd * KINV);
    }
    __syncthreads();

    // Store idx decomposition: idx = it*256+tid, it = nl*4+k ->
    //   row nl = it>>2, ii = (tid>>4) + 16k, j4 = tid&15 (constant).
    const int j4     = tid & 15;
    const int iibase = tid >> 4;
    const v4f* sr4 = (const v4f*)s_rinv;
    const v4f* sx4 = (const v4f*)s_ex;
    v4f r0 = sr4[(iibase +  0) * RSTRIDE + j4];
    v4f r1 = sr4[(iibase + 16) * RSTRIDE + j4];
    v4f r2 = sr4[(iibase + 32) * RSTRIDE + j4];
    v4f r3 = sr4[(iibase + 48) * RSTRIDE + j4];

    v4f* dst = (v4f*)(out + (size_t)(b * 513 + n0) * 4096);
    #pragma unroll 4
    for (int nl = 0; nl < 16; ++nl) {
        v4f ex4 = sx4[nl * 16 + j4];                 // reused for 4 stores
        float ey0 = s_ey[nl * 64 + iibase +  0];
        float ey1 = s_ey[nl * 64 + iibase + 16];
        float ey2 = s_ey[nl * 64 + iibase + 32];
        float ey3 = s_ey[nl * 64 + iibase + 48];
        int base = nl * 1024 + tid;
        dst[base +   0] = (ey0 * ex4) * r0;
        dst[base + 256] = (ey1 * ex4) * r1;
        dst[base + 512] = (ey2 * ex4) * r2;
        dst[base + 768] = (ey3 * ex4) * r3;
    }
}

extern "C" void kernel_launch(void* const* d_in, const int* in_sizes, int n_in,
                              void* d_out, int out_size, void* d_ws, size_t ws_size,
                              hipStream_t stream) {
    const float* pts  = (const float*)d_in[0];   // points [32][512][2]
    const float* st   = (const float*)d_in[1];   // st_sizes [32]
    const float* cood = (const float*)d_in[2];   // cood [64]
    float* out  = (float*)d_out;                 // [32][513][4096] fp32
    float* rinv = (float*)d_ws;                  // 512 KB scratch

    k_denom<<<dim3(1024), dim3(256), 0, stream>>>(pts, st, cood, out, rinv);
    k_write<<<dim3(1024), dim3(256), 0, stream>>>(pts, cood, rinv, out);
}